// Round 15
// baseline (232.806 us; speedup 1.0000x reference)
//
#include <hip/hip_runtime.h>

// R-GCN layer: out[v] = sum_{e: dst[e]=v} norm[e] * (h[src[e]] @ W[rel[e]])
//
// v15: v14's chained-MFMA fused structure with k_fuse TLP doubled. v14
// profile: k_fuse 84.7us latency-bound (MfmaUtil 12.6%, occupancy 25%,
// MFMA-busy only ~11us) -- 3128 waves each running 32 serial rel-run chains.
// v15 splits each wave's rel-range in half: 1024-thread blocks, 16 waves,
// wave (sb, half) handles keys sb*32+half*16..+16 (contiguous -> k_sort
// unchanged). 6256 waves (~24/CU). Halves combine via plain LDS (write,
// barrier, add+store -- no atomics, v13 lesson). Everything else = v14:
//   MFMA1 (16x16x32 bf16): D1[edge][dim] = h_gather x Wfrag
//   MFMA2 (16x16x16 f16):  acc2[dl][dim] += one-hot(norm) x fp16(D1)
//   (MFMA1 C-layout == MFMA2 B-layout: no cross-lane movement)
// payload: x = (dl<<21) | (rel<<16) | src

#define N_NODES 50000
#define N_EDGES 1600000
#define D 64
#define N_REL 32

#define BSHIFT 7                 // 128 nodes per coarse bucket
#define NPB 128
#define NB 391                   // ceil(50000/128)
#define EPB 4096                 // edges per scatter/hist block
#define SC_BLOCKS 391            // ceil(1.6M/4096)
#define SORT_CAP 6144            // bucket capacity (mean 4092, sd 64 -> +32sd)
#define NKEY 256                 // 8 sub-buckets x 32 rels

typedef __attribute__((ext_vector_type(8))) __bf16 bf16x8;
typedef __attribute__((ext_vector_type(4))) __bf16 bf16x4;
typedef __attribute__((ext_vector_type(4))) float f32x4;
typedef __attribute__((ext_vector_type(4))) _Float16 f16x4;

static __device__ inline unsigned short f16_bits(_Float16 v) {
    union { _Float16 f; unsigned short u; } cv; cv.f = v; return cv.u;
}
static __device__ inline _Float16 bits_f16(unsigned short u) {
    union { _Float16 f; unsigned short u; } cv; cv.u = u; return cv.f;
}

// ws layout (bytes):
//   [0x0000, 0x1000)      gcnt[NB] ints
//   [0x1000, 0x2000)      base[NB+1] ints
//   [0x2000, 0x3000)      cursor[NB] ints
//   [0x3000, 0x66000)     runs[NB*257] ints (402 KB)
//   [0x100000, 0xD40000)  payload int2[1.6M] (12.8 MB)
//   [0xD40000, 0xD80000)  Wfrag bf16 [32][2][4][64][8]  (256 KB)
//   [0xD80000, 0x13A0000) hbf bf16 [N_NODES][64]  (6.4 MB)

__global__ __launch_bounds__(512) void k_zeroc(int* __restrict__ gcnt) {
    if (threadIdx.x < NB) gcnt[threadIdx.x] = 0;
}

__global__ __launch_bounds__(256) void k_hist2(const int* __restrict__ dst,
                                               int* __restrict__ gcnt) {
    __shared__ int lc[NB];
    for (int b = threadIdx.x; b < NB; b += 256) lc[b] = 0;
    __syncthreads();
    const int e0 = blockIdx.x * EPB;
    #pragma unroll
    for (int j = 0; j < 16; ++j) {
        int e = e0 + j * 256 + threadIdx.x;
        if (e < N_EDGES) atomicAdd(&lc[dst[e] >> BSHIFT], 1);
    }
    __syncthreads();
    for (int b = threadIdx.x; b < NB; b += 256)
        if (lc[b]) atomicAdd(&gcnt[b], lc[b]);
}

// Exclusive scan of gcnt[0..NB) -> base[0..NB], base[NB]=total; cursor=base.
__global__ __launch_bounds__(512) void k_scanc(const int* __restrict__ gcnt,
                                               int* __restrict__ base,
                                               int* __restrict__ cur) {
    const int t = threadIdx.x;
    const int lane = t & 63;
    const int w = t >> 6;
    int v = (t < NB) ? gcnt[t] : 0;
    int x = v;
    #pragma unroll
    for (int d = 1; d < 64; d <<= 1) {
        int n = __shfl_up(x, d, 64);
        if (lane >= d) x += n;
    }
    __shared__ int wt[8];
    if (lane == 63) wt[w] = x;
    __syncthreads();
    if (t == 0) {
        int run = 0;
        #pragma unroll
        for (int i = 0; i < 8; ++i) { int tmp = wt[i]; wt[i] = run; run += tmp; }
    }
    __syncthreads();
    int excl = x - v + wt[w];
    if (t < NB) { base[t] = excl; cur[t] = excl; }
    if (t == NB - 1) base[NB] = excl + v;
}

// Per-block LDS counting sort of 4096 edges into NB coarse buckets, then
// burst-write contiguous per-bucket runs to globally reserved ranges.
__global__ __launch_bounds__(256) void k_scatter2(
        const int* __restrict__ src, const int* __restrict__ dst,
        const int* __restrict__ rel, const float* __restrict__ norm,
        int* __restrict__ cur, int2* __restrict__ pay) {
    __shared__ int cnt[NB];
    __shared__ int bl[NB + 1];
    __shared__ int gb[NB];
    __shared__ unsigned short bid[EPB];
    __shared__ int2 stage[EPB];
    __shared__ int wt[8];

    const int t = threadIdx.x;
    const int lane = t & 63;
    const int w = t >> 6;
    const int e0 = blockIdx.x * EPB;

    for (int b = t; b < NB; b += 256) cnt[b] = 0;
    __syncthreads();

    // pass 1: count
    #pragma unroll
    for (int j = 0; j < 16; ++j) {
        int e = e0 + j * 256 + t;
        if (e < N_EDGES) atomicAdd(&cnt[dst[e] >> BSHIFT], 1);
    }
    __syncthreads();

    // exclusive scan of cnt[0..NB)
    {
        int x0 = (t < NB) ? cnt[t] : 0;
        int x1 = (t + 256 < NB) ? cnt[t + 256] : 0;
        int s0 = x0, s1 = x1;
        #pragma unroll
        for (int d = 1; d < 64; d <<= 1) {
            int n0 = __shfl_up(s0, d, 64);
            int n1 = __shfl_up(s1, d, 64);
            if (lane >= d) { s0 += n0; s1 += n1; }
        }
        if (lane == 63) { wt[w] = s0; wt[4 + w] = s1; }
        __syncthreads();
        if (t == 0) {
            int run = 0;
            #pragma unroll
            for (int i = 0; i < 8; ++i) { int tmp = wt[i]; wt[i] = run; run += tmp; }
        }
        __syncthreads();
        int ex0 = s0 - x0 + wt[w];
        int ex1 = s1 - x1 + wt[4 + w];
        if (t < NB) bl[t] = ex0;
        if (t + 256 < NB) bl[t + 256] = ex1;
        if (t == 0) {
            int tot = (e0 + EPB <= N_EDGES) ? EPB : (N_EDGES > e0 ? N_EDGES - e0 : 0);
            bl[NB] = tot;
        }
    }
    __syncthreads();

    // reserve global ranges (one atomic per non-empty bucket per block)
    for (int b = t; b < NB; b += 256) {
        int c = bl[b + 1] - bl[b];
        gb[b] = c ? atomicAdd(&cur[b], c) : 0;
    }
    for (int b = t; b < NB; b += 256) cnt[b] = 0;
    __syncthreads();

    // pass 2: stage into LDS in bucket-grouped order
    #pragma unroll
    for (int j = 0; j < 16; ++j) {
        int e = e0 + j * 256 + t;
        if (e < N_EDGES) {
            int dv = dst[e];
            int b = dv >> BSHIFT;
            int r = atomicAdd(&cnt[b], 1);
            int pos = bl[b] + r;
            stage[pos] = make_int2(((dv & (NPB - 1)) << 21) | (rel[e] << 16) | src[e],
                                   __float_as_int(norm[e]));
            bid[pos] = (unsigned short)b;
        }
    }
    __syncthreads();

    // pass 3: burst write to global reserved ranges (coalesced runs)
    const int total = bl[NB];
    for (int p = t; p < total; p += 256) {
        int b = bid[p];
        pay[gb[b] + (p - bl[b])] = stage[p];
    }
}

// One block per bucket: stage edges in LDS, counting-sort by 8-bit key
// (sub-bucket dl>>4, rel) with per-wave counters, write back IN PLACE,
// emit absolute run boundaries runs[b][0..256].
__global__ __launch_bounds__(512) void k_sort(
        const int* __restrict__ base, int2* __restrict__ pay,
        int* __restrict__ runs) {
    __shared__ int2 stage[SORT_CAP];   // 48 KB
    __shared__ int cnt[8][NKEY];       // 8 KB
    __shared__ int wb[8][NKEY];        // 8 KB
    __shared__ int kbase[NKEY];
    __shared__ int wsum[8];

    const int t = threadIdx.x;
    const int lane = t & 63;
    const int w = t >> 6;
    const int b = blockIdx.x;
    const int s = base[b];
    const int e = base[b + 1];
    const int n = min(e - s, SORT_CAP);   // clamp: overflow degrades, never faults

    for (int j = t; j < 8 * NKEY; j += 512) ((int*)cnt)[j] = 0;
    __syncthreads();

    // stage + per-wave count
    for (int j = t; j < n; j += 512) {
        int2 p = pay[s + j];
        stage[j] = p;
        int key = (((p.x >> 25) & 7) << 5) | ((p.x >> 16) & 31);
        atomicAdd(&cnt[w][key], 1);
    }
    __syncthreads();

    // key totals + block-wide exclusive scan over 256 keys
    int tot = 0;
    if (t < NKEY) {
        #pragma unroll
        for (int ww = 0; ww < 8; ++ww) tot += cnt[ww][t];
    }
    int x = tot;
    #pragma unroll
    for (int d = 1; d < 64; d <<= 1) {
        int nn = __shfl_up(x, d, 64);
        if (lane >= d) x += nn;
    }
    if (lane == 63) wsum[w] = x;
    __syncthreads();
    if (t == 0) {
        int run = 0;
        #pragma unroll
        for (int i = 0; i < 8; ++i) { int tmp = wsum[i]; wsum[i] = run; run += tmp; }
    }
    __syncthreads();
    int excl = x - tot + wsum[w];
    if (t < NKEY) kbase[t] = excl;
    __syncthreads();

    // per-wave scatter bases + emit runs
    if (t < NKEY) {
        int run = kbase[t];
        #pragma unroll
        for (int ww = 0; ww < 8; ++ww) { wb[ww][t] = run; run += cnt[ww][t]; }
        runs[b * (NKEY + 1) + t] = s + kbase[t];
    }
    if (t == 0) runs[b * (NKEY + 1) + NKEY] = s + n;
    // barrier BEFORE re-zeroing cnt (v12 race lesson: wb reads all of cnt)
    __syncthreads();
    for (int j = t; j < 8 * NKEY; j += 512) ((int*)cnt)[j] = 0;
    __syncthreads();

    // rank & scatter back in place, key-sorted
    for (int j = t; j < n; j += 512) {
        int2 p = stage[j];
        int key = (((p.x >> 25) & 7) << 5) | ((p.x >> 16) & 31);
        int pos = wb[w][key] + atomicAdd(&cnt[w][key], 1);
        pay[s + pos] = p;
    }
}

// Pack W into per-lane MFMA fragment order (works as A or B slot — the
// 16x16x32 A/B per-lane layouts are symmetric):
// Wfrag[r][kt][ot][lane][j] = bf16( W[r][kt*32 + (lane>>4)*8 + j][ot*16 + (lane&15)] )
__global__ __launch_bounds__(256) void k_wconv(const float* __restrict__ W,
                                               __bf16* __restrict__ Wfrag) {
    const int r = blockIdx.x;
    const int lane = threadIdx.x & 63;
    const int jj = (threadIdx.x >> 6) * 2;   // 2 elems per thread per frag
    const int q = lane >> 4;
    const int m = lane & 15;
    const float* Wr = W + (size_t)r * D * D;
    #pragma unroll
    for (int kt = 0; kt < 2; ++kt) {
        #pragma unroll
        for (int ot = 0; ot < 4; ++ot) {
            size_t dbase = ((((size_t)r * 2 + kt) * 4 + ot) * 64 + lane) * 8 + jj;
            Wfrag[dbase]     = (__bf16)Wr[(kt * 32 + q * 8 + jj) * D + ot * 16 + m];
            Wfrag[dbase + 1] = (__bf16)Wr[(kt * 32 + q * 8 + jj + 1) * D + ot * 16 + m];
        }
    }
}

// h f32 -> hbf bf16 [N_NODES][64] (6.4 MB, L2/L3-resident gather source).
__global__ __launch_bounds__(512) void k_hconv(const float* __restrict__ h,
                                               __bf16* __restrict__ hbf) {
    int idx = blockIdx.x * 512 + threadIdx.x;   // float4 index, 800000 total
    if (idx < N_NODES * 16) {
        float4 v = ((const float4*)h)[idx];
        bf16x4 o;
        o[0] = (__bf16)v.x; o[1] = (__bf16)v.y; o[2] = (__bf16)v.z; o[3] = (__bf16)v.w;
        ((bf16x4*)hbf)[idx] = o;
    }
}

// Fused per-bucket GEMM with chained-MFMA dst-scatter, rel-split waves.
// 1024 threads = 16 waves; wave (sb, half) owns sub-bucket sb (16 dst) and
// rels [half*16, half*16+16). Per 16-edge tile:
//   MFMA1: D1[edge][dim] = h_gather(A) x Wfrag(B)
//   A2 one-hot: S[dl][edge] = norm_e*(dl_e==dl)  [4 shuffles, in-register]
//   MFMA2: acc2[dl][dim] += S x fp16(D1)         [B2 = c1, layout match]
// Halves combine via plain LDS (half0 writes, barrier, half1 adds+stores).
__global__ __launch_bounds__(1024) void k_fuse(
        const unsigned short* __restrict__ hbf, const __bf16* __restrict__ Wfrag,
        const int* __restrict__ runs, const int2* __restrict__ pay,
        float* __restrict__ out) {
    __shared__ int runsL[NKEY + 1];
    __shared__ float accL[8][16][D];   // 32 KB

    const int t = threadIdx.x;
    const int lane = t & 63;
    const int w = t >> 6;        // 0..15
    const int sb = w >> 1;
    const int half = w & 1;
    const int m = lane & 15;
    const int q = lane >> 4;
    const int b = blockIdx.x;

    for (int j = t; j < NKEY + 1; j += 1024) runsL[j] = runs[b * (NKEY + 1) + j];
    __syncthreads();

    const f32x4 vzero = {0.f, 0.f, 0.f, 0.f};
    f32x4 acc2[4];
    #pragma unroll
    for (int ot = 0; ot < 4; ++ot) acc2[ot] = vzero;

    const int kb = sb * 32 + half * 16;
    for (int r = 0; r < 16; ++r) {
        const int rs = runsL[kb + r];
        const int re = runsL[kb + r + 1];
        if (re <= rs) continue;
        const int rel = half * 16 + r;

        // W fragments for this rel: 8 coalesced 16B loads (L2-resident)
        bf16x8 wf[2][4];
        #pragma unroll
        for (int kt = 0; kt < 2; ++kt)
            #pragma unroll
            for (int ot = 0; ot < 4; ++ot)
                wf[kt][ot] = *(const bf16x8*)(Wfrag + ((((size_t)rel * 2 + kt) * 4 + ot) * 64 + lane) * 8);

        const int ntile = (re - rs + 15) >> 4;
        for (int tl = 0; tl < ntile; ++tl) {
            int ei = rs + tl * 16 + m;
            int2 p = pay[min(ei, re - 1)];
            float nvf = (ei < re) ? __int_as_float(p.y) : 0.f;
            int meta = (((p.x >> 21) & 15) << 16) | f16_bits((_Float16)nvf);

            const unsigned short* hrow = hbf + ((size_t)(p.x & 0xFFFF) << 6);
            bf16x8 a0 = *(const bf16x8*)(hrow + q * 8);
            bf16x8 a1 = *(const bf16x8*)(hrow + 32 + q * 8);

            // MFMA1: D1[edge][dim] (lane(m,q): edges q*4+reg, dim m)
            f32x4 c1[4];
            #pragma unroll
            for (int ot = 0; ot < 4; ++ot) {
                c1[ot] = __builtin_amdgcn_mfma_f32_16x16x32_bf16(a0, wf[0][ot], vzero, 0, 0, 0);
                c1[ot] = __builtin_amdgcn_mfma_f32_16x16x32_bf16(a1, wf[1][ot], c1[ot], 0, 0, 0);
            }

            // A2 one-hot: lane(m,q) holds S[row=m][k=q*4+j]
            f16x4 a2;
            #pragma unroll
            for (int j = 0; j < 4; ++j) {
                int sm = __shfl(meta, q * 4 + j, 64);
                _Float16 nv = bits_f16((unsigned short)(sm & 0xFFFF));
                a2[j] = ((sm >> 16) == m) ? nv : (_Float16)0.f;
            }

            // MFMA2: acc2[dl][dim] += S x fp16(D1); B2 = c1 (layout match)
            #pragma unroll
            for (int ot = 0; ot < 4; ++ot) {
                f16x4 b2;
                b2[0] = (_Float16)c1[ot][0];
                b2[1] = (_Float16)c1[ot][1];
                b2[2] = (_Float16)c1[ot][2];
                b2[3] = (_Float16)c1[ot][3];
                acc2[ot] = __builtin_amdgcn_mfma_f32_16x16x16f16(a2, b2, acc2[ot], 0, 0, 0);
            }
        }
    }

    // combine halves: half0 writes LDS, barrier, half1 adds + stores.
    // lane(m,q) acc2[ot][reg] = partial out[sb*16 + q*4+reg][ot*16+m]
    if (half == 0) {
        #pragma unroll
        for (int ot = 0; ot < 4; ++ot)
            #pragma unroll
            for (int reg = 0; reg < 4; ++reg)
                accL[sb][q * 4 + reg][ot * 16 + m] = acc2[ot][reg];
    }
    __syncthreads();
    if (half == 1) {
        const int node_base = b * NPB + sb * 16;
        #pragma unroll
        for (int reg = 0; reg < 4; ++reg) {
            int node = node_base + q * 4 + reg;
            if (node < N_NODES) {
                float* orow = out + (size_t)node * D + m;
                #pragma unroll
                for (int ot = 0; ot < 4; ++ot)
                    orow[ot * 16] = accL[sb][q * 4 + reg][ot * 16 + m] + acc2[ot][reg];
            }
        }
    }
}

extern "C" void kernel_launch(void* const* d_in, const int* in_sizes, int n_in,
                              void* d_out, int out_size, void* d_ws, size_t ws_size,
                              hipStream_t stream) {
    const float* h    = (const float*)d_in[0];
    const float* W    = (const float*)d_in[1];
    const int*   src  = (const int*)d_in[2];
    const int*   dst  = (const int*)d_in[3];
    const int*   rel  = (const int*)d_in[4];
    const float* norm = (const float*)d_in[5];
    float* out = (float*)d_out;

    char* ws = (char*)d_ws;
    int*    gcnt  = (int*)(ws);
    int*    base  = (int*)(ws + 0x1000);
    int*    cur   = (int*)(ws + 0x2000);
    int*    runs  = (int*)(ws + 0x3000);
    int2*   pay   = (int2*)(ws + 0x100000);
    __bf16* Wfrag = (__bf16*)(ws + 0xD40000);
    __bf16* hbf   = (__bf16*)(ws + 0xD80000);

    k_zeroc<<<1, 512, 0, stream>>>(gcnt);
    k_wconv<<<N_REL, 256, 0, stream>>>(W, Wfrag);
    k_hconv<<<1563, 512, 0, stream>>>(h, hbf);
    k_hist2<<<SC_BLOCKS, 256, 0, stream>>>(dst, gcnt);
    k_scanc<<<1, 512, 0, stream>>>(gcnt, base, cur);
    k_scatter2<<<SC_BLOCKS, 256, 0, stream>>>(src, dst, rel, norm, cur, pay);
    k_sort<<<NB, 512, 0, stream>>>(base, pay, runs);
    k_fuse<<<NB, 1024, 0, stream>>>((const unsigned short*)hbf, Wfrag, runs, pay, out);
}

// Round 16
// 224.821 us; speedup vs baseline: 1.0355x; 1.0355x over previous
//
#include <hip/hip_runtime.h>

// R-GCN layer: out[v] = sum_{e: dst[e]=v} norm[e] * (h[src[e]] @ W[rel[e]])
//
// v16: k_fuse restructured around the Wfrag-L2 bottleneck. v15's null result
// (2x waves -> flat 86.8us) proved k_fuse is throughput-bound on an invariant:
// Wfrag re-reads = (#waves x rels/wave) x 8KB = 800MB L2 in BOTH v14/v15.
// v16 runs the rel loop in BLOCK LOCKSTEP: per rel, the block stages the next
// rel's 8KB Wfrag into a double-buffered LDS slab (512 x 16B loads) while
// computing the current rel from LDS (conflict-free ds_read_b128). Wfrag
// traffic: 800 -> 100MB (once per block per rel). 512 thr / 8 waves; wave =
// sub-bucket, accumulates all 32 rels -> v14 direct-store epilogue (no LDS
// combine). Chained-MFMA scatter unchanged:
//   MFMA1 (16x16x32 bf16): D1[edge][dim] = h_gather x Wfrag(LDS)
//   MFMA2 (16x16x16 f16):  acc2[dl][dim] += one-hot(norm) x fp16(D1)
// payload: x = (dl<<21) | (rel<<16) | src

#define N_NODES 50000
#define N_EDGES 1600000
#define D 64
#define N_REL 32

#define BSHIFT 7                 // 128 nodes per coarse bucket
#define NPB 128
#define NB 391                   // ceil(50000/128)
#define EPB 4096                 // edges per scatter/hist block
#define SC_BLOCKS 391            // ceil(1.6M/4096)
#define SORT_CAP 6144            // bucket capacity (mean 4092, sd 64 -> +32sd)
#define NKEY 256                 // 8 sub-buckets x 32 rels

typedef __attribute__((ext_vector_type(8))) __bf16 bf16x8;
typedef __attribute__((ext_vector_type(4))) __bf16 bf16x4;
typedef __attribute__((ext_vector_type(4))) float f32x4;
typedef __attribute__((ext_vector_type(4))) _Float16 f16x4;

static __device__ inline unsigned short f16_bits(_Float16 v) {
    union { _Float16 f; unsigned short u; } cv; cv.f = v; return cv.u;
}
static __device__ inline _Float16 bits_f16(unsigned short u) {
    union { _Float16 f; unsigned short u; } cv; cv.u = u; return cv.f;
}

// ws layout (bytes):
//   [0x0000, 0x1000)      gcnt[NB] ints
//   [0x1000, 0x2000)      base[NB+1] ints
//   [0x2000, 0x3000)      cursor[NB] ints
//   [0x3000, 0x66000)     runs[NB*257] ints (402 KB)
//   [0x100000, 0xD40000)  payload int2[1.6M] (12.8 MB)
//   [0xD40000, 0xD80000)  Wfrag bf16 [32][2][4][64][8]  (256 KB)
//   [0xD80000, 0x13A0000) hbf bf16 [N_NODES][64]  (6.4 MB)

__global__ __launch_bounds__(512) void k_zeroc(int* __restrict__ gcnt) {
    if (threadIdx.x < NB) gcnt[threadIdx.x] = 0;
}

__global__ __launch_bounds__(256) void k_hist2(const int* __restrict__ dst,
                                               int* __restrict__ gcnt) {
    __shared__ int lc[NB];
    for (int b = threadIdx.x; b < NB; b += 256) lc[b] = 0;
    __syncthreads();
    const int e0 = blockIdx.x * EPB;
    #pragma unroll
    for (int j = 0; j < 16; ++j) {
        int e = e0 + j * 256 + threadIdx.x;
        if (e < N_EDGES) atomicAdd(&lc[dst[e] >> BSHIFT], 1);
    }
    __syncthreads();
    for (int b = threadIdx.x; b < NB; b += 256)
        if (lc[b]) atomicAdd(&gcnt[b], lc[b]);
}

// Exclusive scan of gcnt[0..NB) -> base[0..NB], base[NB]=total; cursor=base.
__global__ __launch_bounds__(512) void k_scanc(const int* __restrict__ gcnt,
                                               int* __restrict__ base,
                                               int* __restrict__ cur) {
    const int t = threadIdx.x;
    const int lane = t & 63;
    const int w = t >> 6;
    int v = (t < NB) ? gcnt[t] : 0;
    int x = v;
    #pragma unroll
    for (int d = 1; d < 64; d <<= 1) {
        int n = __shfl_up(x, d, 64);
        if (lane >= d) x += n;
    }
    __shared__ int wt[8];
    if (lane == 63) wt[w] = x;
    __syncthreads();
    if (t == 0) {
        int run = 0;
        #pragma unroll
        for (int i = 0; i < 8; ++i) { int tmp = wt[i]; wt[i] = run; run += tmp; }
    }
    __syncthreads();
    int excl = x - v + wt[w];
    if (t < NB) { base[t] = excl; cur[t] = excl; }
    if (t == NB - 1) base[NB] = excl + v;
}

// Per-block LDS counting sort of 4096 edges into NB coarse buckets, then
// burst-write contiguous per-bucket runs to globally reserved ranges.
__global__ __launch_bounds__(256) void k_scatter2(
        const int* __restrict__ src, const int* __restrict__ dst,
        const int* __restrict__ rel, const float* __restrict__ norm,
        int* __restrict__ cur, int2* __restrict__ pay) {
    __shared__ int cnt[NB];
    __shared__ int bl[NB + 1];
    __shared__ int gb[NB];
    __shared__ unsigned short bid[EPB];
    __shared__ int2 stage[EPB];
    __shared__ int wt[8];

    const int t = threadIdx.x;
    const int lane = t & 63;
    const int w = t >> 6;
    const int e0 = blockIdx.x * EPB;

    for (int b = t; b < NB; b += 256) cnt[b] = 0;
    __syncthreads();

    // pass 1: count
    #pragma unroll
    for (int j = 0; j < 16; ++j) {
        int e = e0 + j * 256 + t;
        if (e < N_EDGES) atomicAdd(&cnt[dst[e] >> BSHIFT], 1);
    }
    __syncthreads();

    // exclusive scan of cnt[0..NB)
    {
        int x0 = (t < NB) ? cnt[t] : 0;
        int x1 = (t + 256 < NB) ? cnt[t + 256] : 0;
        int s0 = x0, s1 = x1;
        #pragma unroll
        for (int d = 1; d < 64; d <<= 1) {
            int n0 = __shfl_up(s0, d, 64);
            int n1 = __shfl_up(s1, d, 64);
            if (lane >= d) { s0 += n0; s1 += n1; }
        }
        if (lane == 63) { wt[w] = s0; wt[4 + w] = s1; }
        __syncthreads();
        if (t == 0) {
            int run = 0;
            #pragma unroll
            for (int i = 0; i < 8; ++i) { int tmp = wt[i]; wt[i] = run; run += tmp; }
        }
        __syncthreads();
        int ex0 = s0 - x0 + wt[w];
        int ex1 = s1 - x1 + wt[4 + w];
        if (t < NB) bl[t] = ex0;
        if (t + 256 < NB) bl[t + 256] = ex1;
        if (t == 0) {
            int tot = (e0 + EPB <= N_EDGES) ? EPB : (N_EDGES > e0 ? N_EDGES - e0 : 0);
            bl[NB] = tot;
        }
    }
    __syncthreads();

    // reserve global ranges (one atomic per non-empty bucket per block)
    for (int b = t; b < NB; b += 256) {
        int c = bl[b + 1] - bl[b];
        gb[b] = c ? atomicAdd(&cur[b], c) : 0;
    }
    for (int b = t; b < NB; b += 256) cnt[b] = 0;
    __syncthreads();

    // pass 2: stage into LDS in bucket-grouped order
    #pragma unroll
    for (int j = 0; j < 16; ++j) {
        int e = e0 + j * 256 + t;
        if (e < N_EDGES) {
            int dv = dst[e];
            int b = dv >> BSHIFT;
            int r = atomicAdd(&cnt[b], 1);
            int pos = bl[b] + r;
            stage[pos] = make_int2(((dv & (NPB - 1)) << 21) | (rel[e] << 16) | src[e],
                                   __float_as_int(norm[e]));
            bid[pos] = (unsigned short)b;
        }
    }
    __syncthreads();

    // pass 3: burst write to global reserved ranges (coalesced runs)
    const int total = bl[NB];
    for (int p = t; p < total; p += 256) {
        int b = bid[p];
        pay[gb[b] + (p - bl[b])] = stage[p];
    }
}

// One block per bucket: stage edges in LDS, counting-sort by 8-bit key
// (sub-bucket dl>>4, rel) with per-wave counters, write back IN PLACE,
// emit absolute run boundaries runs[b][0..256].
__global__ __launch_bounds__(512) void k_sort(
        const int* __restrict__ base, int2* __restrict__ pay,
        int* __restrict__ runs) {
    __shared__ int2 stage[SORT_CAP];   // 48 KB
    __shared__ int cnt[8][NKEY];       // 8 KB
    __shared__ int wb[8][NKEY];        // 8 KB
    __shared__ int kbase[NKEY];
    __shared__ int wsum[8];

    const int t = threadIdx.x;
    const int lane = t & 63;
    const int w = t >> 6;
    const int b = blockIdx.x;
    const int s = base[b];
    const int e = base[b + 1];
    const int n = min(e - s, SORT_CAP);   // clamp: overflow degrades, never faults

    for (int j = t; j < 8 * NKEY; j += 512) ((int*)cnt)[j] = 0;
    __syncthreads();

    // stage + per-wave count
    for (int j = t; j < n; j += 512) {
        int2 p = pay[s + j];
        stage[j] = p;
        int key = (((p.x >> 25) & 7) << 5) | ((p.x >> 16) & 31);
        atomicAdd(&cnt[w][key], 1);
    }
    __syncthreads();

    // key totals + block-wide exclusive scan over 256 keys
    int tot = 0;
    if (t < NKEY) {
        #pragma unroll
        for (int ww = 0; ww < 8; ++ww) tot += cnt[ww][t];
    }
    int x = tot;
    #pragma unroll
    for (int d = 1; d < 64; d <<= 1) {
        int nn = __shfl_up(x, d, 64);
        if (lane >= d) x += nn;
    }
    if (lane == 63) wsum[w] = x;
    __syncthreads();
    if (t == 0) {
        int run = 0;
        #pragma unroll
        for (int i = 0; i < 8; ++i) { int tmp = wsum[i]; wsum[i] = run; run += tmp; }
    }
    __syncthreads();
    int excl = x - tot + wsum[w];
    if (t < NKEY) kbase[t] = excl;
    __syncthreads();

    // per-wave scatter bases + emit runs
    if (t < NKEY) {
        int run = kbase[t];
        #pragma unroll
        for (int ww = 0; ww < 8; ++ww) { wb[ww][t] = run; run += cnt[ww][t]; }
        runs[b * (NKEY + 1) + t] = s + kbase[t];
    }
    if (t == 0) runs[b * (NKEY + 1) + NKEY] = s + n;
    // barrier BEFORE re-zeroing cnt (v12 race lesson: wb reads all of cnt)
    __syncthreads();
    for (int j = t; j < 8 * NKEY; j += 512) ((int*)cnt)[j] = 0;
    __syncthreads();

    // rank & scatter back in place, key-sorted
    for (int j = t; j < n; j += 512) {
        int2 p = stage[j];
        int key = (((p.x >> 25) & 7) << 5) | ((p.x >> 16) & 31);
        int pos = wb[w][key] + atomicAdd(&cnt[w][key], 1);
        pay[s + pos] = p;
    }
}

// Pack W into per-lane MFMA fragment order (works as A or B slot — the
// 16x16x32 A/B per-lane layouts are symmetric):
// Wfrag[r][kt][ot][lane][j] = bf16( W[r][kt*32 + (lane>>4)*8 + j][ot*16 + (lane&15)] )
__global__ __launch_bounds__(256) void k_wconv(const float* __restrict__ W,
                                               __bf16* __restrict__ Wfrag) {
    const int r = blockIdx.x;
    const int lane = threadIdx.x & 63;
    const int jj = (threadIdx.x >> 6) * 2;   // 2 elems per thread per frag
    const int q = lane >> 4;
    const int m = lane & 15;
    const float* Wr = W + (size_t)r * D * D;
    #pragma unroll
    for (int kt = 0; kt < 2; ++kt) {
        #pragma unroll
        for (int ot = 0; ot < 4; ++ot) {
            size_t dbase = ((((size_t)r * 2 + kt) * 4 + ot) * 64 + lane) * 8 + jj;
            Wfrag[dbase]     = (__bf16)Wr[(kt * 32 + q * 8 + jj) * D + ot * 16 + m];
            Wfrag[dbase + 1] = (__bf16)Wr[(kt * 32 + q * 8 + jj + 1) * D + ot * 16 + m];
        }
    }
}

// h f32 -> hbf bf16 [N_NODES][64] (6.4 MB, L2/L3-resident gather source).
__global__ __launch_bounds__(512) void k_hconv(const float* __restrict__ h,
                                               __bf16* __restrict__ hbf) {
    int idx = blockIdx.x * 512 + threadIdx.x;   // float4 index, 800000 total
    if (idx < N_NODES * 16) {
        float4 v = ((const float4*)h)[idx];
        bf16x4 o;
        o[0] = (__bf16)v.x; o[1] = (__bf16)v.y; o[2] = (__bf16)v.z; o[3] = (__bf16)v.w;
        ((bf16x4*)hbf)[idx] = o;
    }
}

// Fused per-bucket GEMM with chained-MFMA dst-scatter, LOCKSTEP-REL.
// 512 threads / 8 waves; wave sb owns sub-bucket sb (16 dst), accumulating
// ALL 32 rels (direct-store epilogue). Per rel iteration: the block stages
// the NEXT rel's 8KB Wfrag into the alternate LDS slab (512 x 16B) while
// computing the current rel; wf fragments come from LDS (ds_read_b128,
// conflict-free). One barrier per rel. Per 16-edge tile:
//   MFMA1: D1[edge][dim] = h_gather(A) x wf(B from LDS)
//   A2 one-hot: S[dl][edge] = norm_e*(dl_e==dl)  [4 shuffles]
//   MFMA2: acc2[dl][dim] += S x fp16(D1)         [B2 = c1, layout match]
__global__ __launch_bounds__(512) void k_fuse(
        const unsigned short* __restrict__ hbf, const __bf16* __restrict__ Wfrag,
        const int* __restrict__ runs, const int2* __restrict__ pay,
        float* __restrict__ out) {
    __shared__ int runsL[NKEY + 1];
    __shared__ __align__(16) unsigned short wbuf[2][4096];   // 16 KB

    const int t = threadIdx.x;
    const int lane = t & 63;
    const int w = t >> 6;        // sub-bucket 0..7
    const int m = lane & 15;
    const int q = lane >> 4;
    const int b = blockIdx.x;

    for (int j = t; j < NKEY + 1; j += 512) runsL[j] = runs[b * (NKEY + 1) + j];
    // prologue: stage Wfrag[rel 0] into wbuf[0]
    ((bf16x8*)wbuf[0])[t] = ((const bf16x8*)Wfrag)[t];
    __syncthreads();

    const f32x4 vzero = {0.f, 0.f, 0.f, 0.f};
    f32x4 acc2[4];
    #pragma unroll
    for (int ot = 0; ot < 4; ++ot) acc2[ot] = vzero;

    for (int r = 0; r < N_REL; ++r) {
        // issue next rel's staging load early (hidden under compute)
        bf16x8 nxt;
        if (r + 1 < N_REL) nxt = ((const bf16x8*)Wfrag)[(r + 1) * 512 + t];

        const int rs = runsL[w * 32 + r];
        const int re = runsL[w * 32 + r + 1];
        const unsigned short* wbp = wbuf[r & 1];

        if (re > rs) {
            // wf fragments from LDS: 8 conflict-free ds_read_b128
            bf16x8 wf[2][4];
            #pragma unroll
            for (int kt = 0; kt < 2; ++kt)
                #pragma unroll
                for (int ot = 0; ot < 4; ++ot)
                    wf[kt][ot] = *(const bf16x8*)(wbp + ((kt * 4 + ot) * 64 + lane) * 8);

            const int ntile = (re - rs + 15) >> 4;
            for (int tl = 0; tl < ntile; ++tl) {
                int ei = rs + tl * 16 + m;
                int2 p = pay[min(ei, re - 1)];
                float nvf = (ei < re) ? __int_as_float(p.y) : 0.f;
                int meta = (((p.x >> 21) & 15) << 16) | f16_bits((_Float16)nvf);

                const unsigned short* hrow = hbf + ((size_t)(p.x & 0xFFFF) << 6);
                bf16x8 a0 = *(const bf16x8*)(hrow + q * 8);
                bf16x8 a1 = *(const bf16x8*)(hrow + 32 + q * 8);

                // MFMA1: D1[edge][dim] (lane(m,q): edges q*4+reg, dim m)
                f32x4 c1[4];
                #pragma unroll
                for (int ot = 0; ot < 4; ++ot) {
                    c1[ot] = __builtin_amdgcn_mfma_f32_16x16x32_bf16(a0, wf[0][ot], vzero, 0, 0, 0);
                    c1[ot] = __builtin_amdgcn_mfma_f32_16x16x32_bf16(a1, wf[1][ot], c1[ot], 0, 0, 0);
                }

                // A2 one-hot: lane(m,q) holds S[row=m][k=q*4+j]
                f16x4 a2;
                #pragma unroll
                for (int j = 0; j < 4; ++j) {
                    int sm = __shfl(meta, q * 4 + j, 64);
                    _Float16 nv = bits_f16((unsigned short)(sm & 0xFFFF));
                    a2[j] = ((sm >> 16) == m) ? nv : (_Float16)0.f;
                }

                // MFMA2: acc2[dl][dim] += S x fp16(D1); B2 = c1 (layout match)
                #pragma unroll
                for (int ot = 0; ot < 4; ++ot) {
                    f16x4 b2;
                    b2[0] = (_Float16)c1[ot][0];
                    b2[1] = (_Float16)c1[ot][1];
                    b2[2] = (_Float16)c1[ot][2];
                    b2[3] = (_Float16)c1[ot][3];
                    acc2[ot] = __builtin_amdgcn_mfma_f32_16x16x16f16(a2, b2, acc2[ot], 0, 0, 0);
                }
            }
        }

        // write next buffer, then one barrier per rel:
        //  - readers of wbuf[(r+1)&1] (rel r-1) all passed the PREVIOUS barrier
        //  - next iteration's readers of wbuf[(r+1)&1] wait on THIS barrier
        if (r + 1 < N_REL) ((bf16x8*)wbuf[(r + 1) & 1])[t] = nxt;
        __syncthreads();
    }

    // epilogue: lane(m,q) holds acc2[ot][reg] = out[sb*16 + q*4+reg][ot*16+m]
    const int node_base = b * NPB + w * 16;
    #pragma unroll
    for (int reg = 0; reg < 4; ++reg) {
        int node = node_base + q * 4 + reg;
        if (node < N_NODES) {
            float* orow = out + (size_t)node * D + m;
            #pragma unroll
            for (int ot = 0; ot < 4; ++ot)
                orow[ot * 16] = acc2[ot][reg];
        }
    }
}

extern "C" void kernel_launch(void* const* d_in, const int* in_sizes, int n_in,
                              void* d_out, int out_size, void* d_ws, size_t ws_size,
                              hipStream_t stream) {
    const float* h    = (const float*)d_in[0];
    const float* W    = (const float*)d_in[1];
    const int*   src  = (const int*)d_in[2];
    const int*   dst  = (const int*)d_in[3];
    const int*   rel  = (const int*)d_in[4];
    const float* norm = (const float*)d_in[5];
    float* out = (float*)d_out;

    char* ws = (char*)d_ws;
    int*    gcnt  = (int*)(ws);
    int*    base  = (int*)(ws + 0x1000);
    int*    cur   = (int*)(ws + 0x2000);
    int*    runs  = (int*)(ws + 0x3000);
    int2*   pay   = (int2*)(ws + 0x100000);
    __bf16* Wfrag = (__bf16*)(ws + 0xD40000);
    __bf16* hbf   = (__bf16*)(ws + 0xD80000);

    k_zeroc<<<1, 512, 0, stream>>>(gcnt);
    k_wconv<<<N_REL, 256, 0, stream>>>(W, Wfrag);
    k_hconv<<<1563, 512, 0, stream>>>(h, hbf);
    k_hist2<<<SC_BLOCKS, 256, 0, stream>>>(dst, gcnt);
    k_scanc<<<1, 512, 0, stream>>>(gcnt, base, cur);
    k_scatter2<<<SC_BLOCKS, 256, 0, stream>>>(src, dst, rel, norm, cur, pay);
    k_sort<<<NB, 512, 0, stream>>>(base, pay, runs);
    k_fuse<<<NB, 512, 0, stream>>>((const unsigned short*)hbf, Wfrag, runs, pay, out);
}

// Round 17
// 215.843 us; speedup vs baseline: 1.0786x; 1.0416x over previous
//
#include <hip/hip_runtime.h>

// R-GCN layer: out[v] = sum_{e: dst[e]=v} norm[e] * (h[src[e]] @ W[rel[e]])
//
// v17: v16 + 2-deep software pipeline in k_fuse. v16 post-mortem: with the
// Wfrag-L2 traffic gone (86.8->77.7us), k_fuse is bound by the per-tile
// serial chain pay(L2)->hrow(L2)->MFMA1->shuffle->MFMA2 at ~1.5 blocks/CU.
// The item sequence (run,tile) is fully determined by runsL (LDS), so v17
// prefetches ACROSS run/rel boundaries: while computing item i, issue hrow
// gathers for item i+1 (payload loaded during i-1) and payload for i+2.
// Loads stay in flight across the per-rel barrier (only wbuf ds_reads are
// barrier-ordered); the lockstep Wfrag double-buffer staging is untouched.
//   MFMA1 (16x16x32 bf16): D1[edge][dim] = h_gather x Wfrag(LDS)
//   MFMA2 (16x16x16 f16):  acc2[dl][dim] += one-hot(norm) x fp16(D1)
// payload: x = (dl<<21) | (rel<<16) | src

#define N_NODES 50000
#define N_EDGES 1600000
#define D 64
#define N_REL 32

#define BSHIFT 7                 // 128 nodes per coarse bucket
#define NPB 128
#define NB 391                   // ceil(50000/128)
#define EPB 4096                 // edges per scatter/hist block
#define SC_BLOCKS 391            // ceil(1.6M/4096)
#define SORT_CAP 6144            // bucket capacity (mean 4092, sd 64 -> +32sd)
#define NKEY 256                 // 8 sub-buckets x 32 rels

typedef __attribute__((ext_vector_type(8))) __bf16 bf16x8;
typedef __attribute__((ext_vector_type(4))) __bf16 bf16x4;
typedef __attribute__((ext_vector_type(4))) float f32x4;
typedef __attribute__((ext_vector_type(4))) _Float16 f16x4;

static __device__ inline unsigned short f16_bits(_Float16 v) {
    union { _Float16 f; unsigned short u; } cv; cv.f = v; return cv.u;
}
static __device__ inline _Float16 bits_f16(unsigned short u) {
    union { _Float16 f; unsigned short u; } cv; cv.u = u; return cv.f;
}

// ws layout (bytes):
//   [0x0000, 0x1000)      gcnt[NB] ints
//   [0x1000, 0x2000)      base[NB+1] ints
//   [0x2000, 0x3000)      cursor[NB] ints
//   [0x3000, 0x66000)     runs[NB*257] ints (402 KB)
//   [0x100000, 0xD40000)  payload int2[1.6M] (12.8 MB)
//   [0xD40000, 0xD80000)  Wfrag bf16 [32][2][4][64][8]  (256 KB)
//   [0xD80000, 0x13A0000) hbf bf16 [N_NODES][64]  (6.4 MB)

__global__ __launch_bounds__(512) void k_zeroc(int* __restrict__ gcnt) {
    if (threadIdx.x < NB) gcnt[threadIdx.x] = 0;
}

__global__ __launch_bounds__(256) void k_hist2(const int* __restrict__ dst,
                                               int* __restrict__ gcnt) {
    __shared__ int lc[NB];
    for (int b = threadIdx.x; b < NB; b += 256) lc[b] = 0;
    __syncthreads();
    const int e0 = blockIdx.x * EPB;
    #pragma unroll
    for (int j = 0; j < 16; ++j) {
        int e = e0 + j * 256 + threadIdx.x;
        if (e < N_EDGES) atomicAdd(&lc[dst[e] >> BSHIFT], 1);
    }
    __syncthreads();
    for (int b = threadIdx.x; b < NB; b += 256)
        if (lc[b]) atomicAdd(&gcnt[b], lc[b]);
}

// Exclusive scan of gcnt[0..NB) -> base[0..NB], base[NB]=total; cursor=base.
__global__ __launch_bounds__(512) void k_scanc(const int* __restrict__ gcnt,
                                               int* __restrict__ base,
                                               int* __restrict__ cur) {
    const int t = threadIdx.x;
    const int lane = t & 63;
    const int w = t >> 6;
    int v = (t < NB) ? gcnt[t] : 0;
    int x = v;
    #pragma unroll
    for (int d = 1; d < 64; d <<= 1) {
        int n = __shfl_up(x, d, 64);
        if (lane >= d) x += n;
    }
    __shared__ int wt[8];
    if (lane == 63) wt[w] = x;
    __syncthreads();
    if (t == 0) {
        int run = 0;
        #pragma unroll
        for (int i = 0; i < 8; ++i) { int tmp = wt[i]; wt[i] = run; run += tmp; }
    }
    __syncthreads();
    int excl = x - v + wt[w];
    if (t < NB) { base[t] = excl; cur[t] = excl; }
    if (t == NB - 1) base[NB] = excl + v;
}

// Per-block LDS counting sort of 4096 edges into NB coarse buckets, then
// burst-write contiguous per-bucket runs to globally reserved ranges.
__global__ __launch_bounds__(256) void k_scatter2(
        const int* __restrict__ src, const int* __restrict__ dst,
        const int* __restrict__ rel, const float* __restrict__ norm,
        int* __restrict__ cur, int2* __restrict__ pay) {
    __shared__ int cnt[NB];
    __shared__ int bl[NB + 1];
    __shared__ int gb[NB];
    __shared__ unsigned short bid[EPB];
    __shared__ int2 stage[EPB];
    __shared__ int wt[8];

    const int t = threadIdx.x;
    const int lane = t & 63;
    const int w = t >> 6;
    const int e0 = blockIdx.x * EPB;

    for (int b = t; b < NB; b += 256) cnt[b] = 0;
    __syncthreads();

    // pass 1: count
    #pragma unroll
    for (int j = 0; j < 16; ++j) {
        int e = e0 + j * 256 + t;
        if (e < N_EDGES) atomicAdd(&cnt[dst[e] >> BSHIFT], 1);
    }
    __syncthreads();

    // exclusive scan of cnt[0..NB)
    {
        int x0 = (t < NB) ? cnt[t] : 0;
        int x1 = (t + 256 < NB) ? cnt[t + 256] : 0;
        int s0 = x0, s1 = x1;
        #pragma unroll
        for (int d = 1; d < 64; d <<= 1) {
            int n0 = __shfl_up(s0, d, 64);
            int n1 = __shfl_up(s1, d, 64);
            if (lane >= d) { s0 += n0; s1 += n1; }
        }
        if (lane == 63) { wt[w] = s0; wt[4 + w] = s1; }
        __syncthreads();
        if (t == 0) {
            int run = 0;
            #pragma unroll
            for (int i = 0; i < 8; ++i) { int tmp = wt[i]; wt[i] = run; run += tmp; }
        }
        __syncthreads();
        int ex0 = s0 - x0 + wt[w];
        int ex1 = s1 - x1 + wt[4 + w];
        if (t < NB) bl[t] = ex0;
        if (t + 256 < NB) bl[t + 256] = ex1;
        if (t == 0) {
            int tot = (e0 + EPB <= N_EDGES) ? EPB : (N_EDGES > e0 ? N_EDGES - e0 : 0);
            bl[NB] = tot;
        }
    }
    __syncthreads();

    // reserve global ranges (one atomic per non-empty bucket per block)
    for (int b = t; b < NB; b += 256) {
        int c = bl[b + 1] - bl[b];
        gb[b] = c ? atomicAdd(&cur[b], c) : 0;
    }
    for (int b = t; b < NB; b += 256) cnt[b] = 0;
    __syncthreads();

    // pass 2: stage into LDS in bucket-grouped order
    #pragma unroll
    for (int j = 0; j < 16; ++j) {
        int e = e0 + j * 256 + t;
        if (e < N_EDGES) {
            int dv = dst[e];
            int b = dv >> BSHIFT;
            int r = atomicAdd(&cnt[b], 1);
            int pos = bl[b] + r;
            stage[pos] = make_int2(((dv & (NPB - 1)) << 21) | (rel[e] << 16) | src[e],
                                   __float_as_int(norm[e]));
            bid[pos] = (unsigned short)b;
        }
    }
    __syncthreads();

    // pass 3: burst write to global reserved ranges (coalesced runs)
    const int total = bl[NB];
    for (int p = t; p < total; p += 256) {
        int b = bid[p];
        pay[gb[b] + (p - bl[b])] = stage[p];
    }
}

// One block per bucket: stage edges in LDS, counting-sort by 8-bit key
// (sub-bucket dl>>4, rel) with per-wave counters, write back IN PLACE,
// emit absolute run boundaries runs[b][0..256].
__global__ __launch_bounds__(512) void k_sort(
        const int* __restrict__ base, int2* __restrict__ pay,
        int* __restrict__ runs) {
    __shared__ int2 stage[SORT_CAP];   // 48 KB
    __shared__ int cnt[8][NKEY];       // 8 KB
    __shared__ int wb[8][NKEY];        // 8 KB
    __shared__ int kbase[NKEY];
    __shared__ int wsum[8];

    const int t = threadIdx.x;
    const int lane = t & 63;
    const int w = t >> 6;
    const int b = blockIdx.x;
    const int s = base[b];
    const int e = base[b + 1];
    const int n = min(e - s, SORT_CAP);   // clamp: overflow degrades, never faults

    for (int j = t; j < 8 * NKEY; j += 512) ((int*)cnt)[j] = 0;
    __syncthreads();

    // stage + per-wave count
    for (int j = t; j < n; j += 512) {
        int2 p = pay[s + j];
        stage[j] = p;
        int key = (((p.x >> 25) & 7) << 5) | ((p.x >> 16) & 31);
        atomicAdd(&cnt[w][key], 1);
    }
    __syncthreads();

    // key totals + block-wide exclusive scan over 256 keys
    int tot = 0;
    if (t < NKEY) {
        #pragma unroll
        for (int ww = 0; ww < 8; ++ww) tot += cnt[ww][t];
    }
    int x = tot;
    #pragma unroll
    for (int d = 1; d < 64; d <<= 1) {
        int nn = __shfl_up(x, d, 64);
        if (lane >= d) x += nn;
    }
    if (lane == 63) wsum[w] = x;
    __syncthreads();
    if (t == 0) {
        int run = 0;
        #pragma unroll
        for (int i = 0; i < 8; ++i) { int tmp = wsum[i]; wsum[i] = run; run += tmp; }
    }
    __syncthreads();
    int excl = x - tot + wsum[w];
    if (t < NKEY) kbase[t] = excl;
    __syncthreads();

    // per-wave scatter bases + emit runs
    if (t < NKEY) {
        int run = kbase[t];
        #pragma unroll
        for (int ww = 0; ww < 8; ++ww) { wb[ww][t] = run; run += cnt[ww][t]; }
        runs[b * (NKEY + 1) + t] = s + kbase[t];
    }
    if (t == 0) runs[b * (NKEY + 1) + NKEY] = s + n;
    // barrier BEFORE re-zeroing cnt (v12 race lesson: wb reads all of cnt)
    __syncthreads();
    for (int j = t; j < 8 * NKEY; j += 512) ((int*)cnt)[j] = 0;
    __syncthreads();

    // rank & scatter back in place, key-sorted
    for (int j = t; j < n; j += 512) {
        int2 p = stage[j];
        int key = (((p.x >> 25) & 7) << 5) | ((p.x >> 16) & 31);
        int pos = wb[w][key] + atomicAdd(&cnt[w][key], 1);
        pay[s + pos] = p;
    }
}

// Pack W into per-lane MFMA fragment order (works as A or B slot — the
// 16x16x32 A/B per-lane layouts are symmetric):
// Wfrag[r][kt][ot][lane][j] = bf16( W[r][kt*32 + (lane>>4)*8 + j][ot*16 + (lane&15)] )
__global__ __launch_bounds__(256) void k_wconv(const float* __restrict__ W,
                                               __bf16* __restrict__ Wfrag) {
    const int r = blockIdx.x;
    const int lane = threadIdx.x & 63;
    const int jj = (threadIdx.x >> 6) * 2;   // 2 elems per thread per frag
    const int q = lane >> 4;
    const int m = lane & 15;
    const float* Wr = W + (size_t)r * D * D;
    #pragma unroll
    for (int kt = 0; kt < 2; ++kt) {
        #pragma unroll
        for (int ot = 0; ot < 4; ++ot) {
            size_t dbase = ((((size_t)r * 2 + kt) * 4 + ot) * 64 + lane) * 8 + jj;
            Wfrag[dbase]     = (__bf16)Wr[(kt * 32 + q * 8 + jj) * D + ot * 16 + m];
            Wfrag[dbase + 1] = (__bf16)Wr[(kt * 32 + q * 8 + jj + 1) * D + ot * 16 + m];
        }
    }
}

// h f32 -> hbf bf16 [N_NODES][64] (6.4 MB, L2/L3-resident gather source).
__global__ __launch_bounds__(512) void k_hconv(const float* __restrict__ h,
                                               __bf16* __restrict__ hbf) {
    int idx = blockIdx.x * 512 + threadIdx.x;   // float4 index, 800000 total
    if (idx < N_NODES * 16) {
        float4 v = ((const float4*)h)[idx];
        bf16x4 o;
        o[0] = (__bf16)v.x; o[1] = (__bf16)v.y; o[2] = (__bf16)v.z; o[3] = (__bf16)v.w;
        ((bf16x4*)hbf)[idx] = o;
    }
}

// Fused per-bucket GEMM with chained-MFMA dst-scatter, lockstep-rel Wfrag
// staging, and a 2-deep software pipeline over (run,tile) items:
//   item i computing | item i+1 hrow gathers in flight | item i+2 pay in flight
// Loads cross the per-rel barrier legally (only wbuf ds_reads are ordered).
// 512 thr / 8 waves; wave sb owns sub-bucket sb, accumulates all 32 rels.
__global__ __launch_bounds__(512) void k_fuse(
        const unsigned short* __restrict__ hbf, const __bf16* __restrict__ Wfrag,
        const int* __restrict__ runs, const int2* __restrict__ pay,
        float* __restrict__ out) {
    __shared__ int runsL[NKEY + 1];
    __shared__ __align__(16) unsigned short wbuf[2][4096];   // 16 KB

    const int t = threadIdx.x;
    const int lane = t & 63;
    const int w = t >> 6;        // sub-bucket 0..7
    const int m = lane & 15;
    const int q = lane >> 4;
    const int b = blockIdx.x;

    for (int j = t; j < NKEY + 1; j += 512) runsL[j] = runs[b * (NKEY + 1) + j];
    ((bf16x8*)wbuf[0])[t] = ((const bf16x8*)Wfrag)[t];
    __syncthreads();

    const f32x4 vzero = {0.f, 0.f, 0.f, 0.f};
    f32x4 acc2[4];
    #pragma unroll
    for (int ot = 0; ot < 4; ++ot) acc2[ot] = vzero;

    const int kb = w * 32;

    // ---- pipeline state ----
    // iterator (pr, ptl): item whose PAYLOAD is issued next (wave-uniform)
    int pr = 0, ptl = 0, prs = 0, pre_ = 0;
    while (pr < N_REL) { prs = runsL[kb + pr]; pre_ = runsL[kb + pr + 1]; if (pre_ > prs) break; ++pr; }

    int cr = N_REL, cmask = 0;       // current item (compute-ready)
    int2 p_cur; bf16x8 a0c, a1c;
    int nrel = N_REL, nmask = 0;     // next item (payload in flight)
    int2 p_nxt;

    if (pr < N_REL) {
        // bootstrap item A (serial prologue)
        int ei = prs + ptl * 16 + m;
        p_cur = pay[min(ei, pre_ - 1)];
        cmask = (ei < pre_);
        cr = pr;
        ++ptl;
        if (prs + ptl * 16 >= pre_) {
            ++pr; ptl = 0;
            while (pr < N_REL) { prs = runsL[kb + pr]; pre_ = runsL[kb + pr + 1]; if (pre_ > prs) break; ++pr; }
        }
        const unsigned short* hrow = hbf + ((size_t)(p_cur.x & 0xFFFF) << 6);
        a0c = *(const bf16x8*)(hrow + q * 8);
        a1c = *(const bf16x8*)(hrow + 32 + q * 8);
        // item B payload
        if (pr < N_REL) {
            int ei2 = prs + ptl * 16 + m;
            p_nxt = pay[min(ei2, pre_ - 1)];
            nmask = (ei2 < pre_);
            nrel = pr;
            ++ptl;
            if (prs + ptl * 16 >= pre_) {
                ++pr; ptl = 0;
                while (pr < N_REL) { prs = runsL[kb + pr]; pre_ = runsL[kb + pr + 1]; if (pre_ > prs) break; ++pr; }
            }
        }
    }

    for (int r = 0; r < N_REL; ++r) {
        // issue next rel's Wfrag staging load early (hidden under compute)
        bf16x8 stg;
        if (r + 1 < N_REL) stg = ((const bf16x8*)Wfrag)[(r + 1) * 512 + t];

        if (cr == r) {
            const unsigned short* wbp = wbuf[r & 1];
            bf16x8 wf[2][4];
            #pragma unroll
            for (int kt = 0; kt < 2; ++kt)
                #pragma unroll
                for (int ot = 0; ot < 4; ++ot)
                    wf[kt][ot] = *(const bf16x8*)(wbp + ((kt * 4 + ot) * 64 + lane) * 8);

            while (cr == r) {
                // promote next item: start its hrow gathers now
                int2 p_b = p_nxt;
                int brel = nrel, bmask = nmask;
                bf16x8 a0n, a1n;
                if (brel < N_REL) {
                    const unsigned short* hrn = hbf + ((size_t)(p_b.x & 0xFFFF) << 6);
                    a0n = *(const bf16x8*)(hrn + q * 8);
                    a1n = *(const bf16x8*)(hrn + 32 + q * 8);
                }
                // issue payload for the item after next
                if (pr < N_REL) {
                    int ei2 = prs + ptl * 16 + m;
                    p_nxt = pay[min(ei2, pre_ - 1)];
                    nmask = (ei2 < pre_);
                    nrel = pr;
                    ++ptl;
                    if (prs + ptl * 16 >= pre_) {
                        ++pr; ptl = 0;
                        while (pr < N_REL) { prs = runsL[kb + pr]; pre_ = runsL[kb + pr + 1]; if (pre_ > prs) break; ++pr; }
                    }
                } else {
                    nrel = N_REL;
                }

                // compute CURRENT item
                float nvf = cmask ? __int_as_float(p_cur.y) : 0.f;
                int meta = (((p_cur.x >> 21) & 15) << 16) | f16_bits((_Float16)nvf);

                f32x4 c1[4];
                #pragma unroll
                for (int ot = 0; ot < 4; ++ot) {
                    c1[ot] = __builtin_amdgcn_mfma_f32_16x16x32_bf16(a0c, wf[0][ot], vzero, 0, 0, 0);
                    c1[ot] = __builtin_amdgcn_mfma_f32_16x16x32_bf16(a1c, wf[1][ot], c1[ot], 0, 0, 0);
                }

                f16x4 a2;
                #pragma unroll
                for (int j = 0; j < 4; ++j) {
                    int sm = __shfl(meta, q * 4 + j, 64);
                    _Float16 nv = bits_f16((unsigned short)(sm & 0xFFFF));
                    a2[j] = ((sm >> 16) == m) ? nv : (_Float16)0.f;
                }

                #pragma unroll
                for (int ot = 0; ot < 4; ++ot) {
                    f16x4 b2;
                    b2[0] = (_Float16)c1[ot][0];
                    b2[1] = (_Float16)c1[ot][1];
                    b2[2] = (_Float16)c1[ot][2];
                    b2[3] = (_Float16)c1[ot][3];
                    acc2[ot] = __builtin_amdgcn_mfma_f32_16x16x16f16(a2, b2, acc2[ot], 0, 0, 0);
                }

                // rotate pipeline
                p_cur = p_b; cmask = bmask; cr = brel;
                a0c = a0n; a1c = a1n;
            }
        }

        if (r + 1 < N_REL) ((bf16x8*)wbuf[(r + 1) & 1])[t] = stg;
        __syncthreads();
    }

    // epilogue: lane(m,q) holds acc2[ot][reg] = out[sb*16 + q*4+reg][ot*16+m]
    const int node_base = b * NPB + w * 16;
    #pragma unroll
    for (int reg = 0; reg < 4; ++reg) {
        int node = node_base + q * 4 + reg;
        if (node < N_NODES) {
            float* orow = out + (size_t)node * D + m;
            #pragma unroll
            for (int ot = 0; ot < 4; ++ot)
                orow[ot * 16] = acc2[ot][reg];
        }
    }
}

extern "C" void kernel_launch(void* const* d_in, const int* in_sizes, int n_in,
                              void* d_out, int out_size, void* d_ws, size_t ws_size,
                              hipStream_t stream) {
    const float* h    = (const float*)d_in[0];
    const float* W    = (const float*)d_in[1];
    const int*   src  = (const int*)d_in[2];
    const int*   dst  = (const int*)d_in[3];
    const int*   rel  = (const int*)d_in[4];
    const float* norm = (const float*)d_in[5];
    float* out = (float*)d_out;

    char* ws = (char*)d_ws;
    int*    gcnt  = (int*)(ws);
    int*    base  = (int*)(ws + 0x1000);
    int*    cur   = (int*)(ws + 0x2000);
    int*    runs  = (int*)(ws + 0x3000);
    int2*   pay   = (int2*)(ws + 0x100000);
    __bf16* Wfrag = (__bf16*)(ws + 0xD40000);
    __bf16* hbf   = (__bf16*)(ws + 0xD80000);

    k_zeroc<<<1, 512, 0, stream>>>(gcnt);
    k_wconv<<<N_REL, 256, 0, stream>>>(W, Wfrag);
    k_hconv<<<1563, 512, 0, stream>>>(h, hbf);
    k_hist2<<<SC_BLOCKS, 256, 0, stream>>>(dst, gcnt);
    k_scanc<<<1, 512, 0, stream>>>(gcnt, base, cur);
    k_scatter2<<<SC_BLOCKS, 256, 0, stream>>>(src, dst, rel, norm, cur, pay);
    k_sort<<<NB, 512, 0, stream>>>(base, pay, runs);
    k_fuse<<<NB, 512, 0, stream>>>((const unsigned short*)hbf, Wfrag, runs, pay, out);
}

// Round 18
// 193.248 us; speedup vs baseline: 1.2047x; 1.1169x over previous
//
#include <hip/hip_runtime.h>

// R-GCN layer: out[v] = sum_{e: dst[e]=v} norm[e] * (h[src[e]] @ W[rel[e]])
//
// v18: v17's compute pipeline (unchanged) + preprocessing-chain elimination.
// v17 showed k_fuse 70.9us but ~145us spread across 7 support kernels +
// launch gaps. v18: (1) FIXED-CAPACITY buckets (CAP=6144 = +32sd) make
// base[b] = b*CAP a constant -> k_hist2 and k_scanc deleted outright;
// (2) zeroc+wconv+hconv merged into one k_init (disjoint block ranges).
// Launches: 8 -> 4 (init, scatter2, sort, fuse). Hot kernels' inner logic
// byte-identical to v17:
//   k_scatter2 LDS counting sort of 4096 edges -> burst writes (cur-reserve)
//   k_sort     per-bucket 256-key sort (8 sub-buckets x 32 rels) + runs[]
//   k_fuse     chained-MFMA scatter, lockstep-rel Wfrag LDS staging,
//              2-deep (run,tile) software pipeline
// payload: x = (dl<<21) | (rel<<16) | src

#define N_NODES 50000
#define N_EDGES 1600000
#define D 64
#define N_REL 32

#define BSHIFT 7                 // 128 nodes per coarse bucket
#define NPB 128
#define NB 391                   // ceil(50000/128)
#define EPB 4096                 // edges per scatter block
#define SC_BLOCKS 391            // ceil(1.6M/4096)
#define BCAP 6144                // fixed bucket capacity (mean 4092, +32sd)
#define SORT_CAP 6144
#define NKEY 256                 // 8 sub-buckets x 32 rels

#define HCONV_BLOCKS 1563        // ceil(800000/512)
#define INIT_BLOCKS (HCONV_BLOCKS + N_REL + 1)

typedef __attribute__((ext_vector_type(8))) __bf16 bf16x8;
typedef __attribute__((ext_vector_type(4))) __bf16 bf16x4;
typedef __attribute__((ext_vector_type(4))) float f32x4;
typedef __attribute__((ext_vector_type(4))) _Float16 f16x4;

static __device__ inline unsigned short f16_bits(_Float16 v) {
    union { _Float16 f; unsigned short u; } cv; cv.f = v; return cv.u;
}
static __device__ inline _Float16 bits_f16(unsigned short u) {
    union { _Float16 f; unsigned short u; } cv; cv.u = u; return cv.f;
}

// ws layout (bytes):
//   [0x2000, 0x3000)        cursor[NB] ints
//   [0x3000, 0x66000)       runs[NB*257] ints (402 KB)
//   [0x100000, 0x1354C00)   payload int2[NB*BCAP]  (19.2 MB, fixed-cap)
//   [0x1400000, 0x1440000)  Wfrag bf16 [32][2][4][64][8]  (256 KB)
//   [0x1480000, 0x1AC0000)  hbf bf16 [N_NODES][64]  (6.4 MB)

// Merged init: blocks [0,1563) convert h->bf16; [1563,1595) pack W frags;
// block 1595 inits cursors to b*BCAP.
__global__ __launch_bounds__(512) void k_init(
        const float* __restrict__ h, __bf16* __restrict__ hbf,
        const float* __restrict__ W, __bf16* __restrict__ Wfrag,
        int* __restrict__ cur) {
    const int blk = blockIdx.x;
    if (blk < HCONV_BLOCKS) {
        int idx = blk * 512 + threadIdx.x;   // float4 index, 800000 total
        if (idx < N_NODES * 16) {
            float4 v = ((const float4*)h)[idx];
            bf16x4 o;
            o[0] = (__bf16)v.x; o[1] = (__bf16)v.y; o[2] = (__bf16)v.z; o[3] = (__bf16)v.w;
            ((bf16x4*)hbf)[idx] = o;
        }
    } else if (blk < HCONV_BLOCKS + N_REL) {
        const int r = blk - HCONV_BLOCKS;
        const int lane = threadIdx.x & 63;
        const int jj = threadIdx.x >> 6;     // 0..7
        const int q = lane >> 4;
        const int m = lane & 15;
        const float* Wr = W + (size_t)r * D * D;
        #pragma unroll
        for (int kt = 0; kt < 2; ++kt) {
            #pragma unroll
            for (int ot = 0; ot < 4; ++ot) {
                size_t dbase = ((((size_t)r * 2 + kt) * 4 + ot) * 64 + lane) * 8 + jj;
                Wfrag[dbase] = (__bf16)Wr[(kt * 32 + q * 8 + jj) * D + ot * 16 + m];
            }
        }
    } else {
        if (threadIdx.x < NB) cur[threadIdx.x] = threadIdx.x * BCAP;
    }
}

// Per-block LDS counting sort of 4096 edges into NB coarse buckets, then
// burst-write contiguous per-bucket runs to globally reserved (fixed-cap)
// ranges. payload: x = (dl<<21) | (rel<<16) | src, y = bits(norm)
__global__ __launch_bounds__(256) void k_scatter2(
        const int* __restrict__ src, const int* __restrict__ dst,
        const int* __restrict__ rel, const float* __restrict__ norm,
        int* __restrict__ cur, int2* __restrict__ pay) {
    __shared__ int cnt[NB];
    __shared__ int bl[NB + 1];
    __shared__ int gb[NB];
    __shared__ unsigned short bid[EPB];
    __shared__ int2 stage[EPB];
    __shared__ int wt[8];

    const int t = threadIdx.x;
    const int lane = t & 63;
    const int w = t >> 6;
    const int e0 = blockIdx.x * EPB;

    for (int b = t; b < NB; b += 256) cnt[b] = 0;
    __syncthreads();

    // pass 1: count
    #pragma unroll
    for (int j = 0; j < 16; ++j) {
        int e = e0 + j * 256 + t;
        if (e < N_EDGES) atomicAdd(&cnt[dst[e] >> BSHIFT], 1);
    }
    __syncthreads();

    // exclusive scan of cnt[0..NB)
    {
        int x0 = (t < NB) ? cnt[t] : 0;
        int x1 = (t + 256 < NB) ? cnt[t + 256] : 0;
        int s0 = x0, s1 = x1;
        #pragma unroll
        for (int d = 1; d < 64; d <<= 1) {
            int n0 = __shfl_up(s0, d, 64);
            int n1 = __shfl_up(s1, d, 64);
            if (lane >= d) { s0 += n0; s1 += n1; }
        }
        if (lane == 63) { wt[w] = s0; wt[4 + w] = s1; }
        __syncthreads();
        if (t == 0) {
            int run = 0;
            #pragma unroll
            for (int i = 0; i < 8; ++i) { int tmp = wt[i]; wt[i] = run; run += tmp; }
        }
        __syncthreads();
        int ex0 = s0 - x0 + wt[w];
        int ex1 = s1 - x1 + wt[4 + w];
        if (t < NB) bl[t] = ex0;
        if (t + 256 < NB) bl[t + 256] = ex1;
        if (t == 0) {
            int tot = (e0 + EPB <= N_EDGES) ? EPB : (N_EDGES > e0 ? N_EDGES - e0 : 0);
            bl[NB] = tot;
        }
    }
    __syncthreads();

    // reserve global ranges (one atomic per non-empty bucket per block)
    for (int b = t; b < NB; b += 256) {
        int c = bl[b + 1] - bl[b];
        gb[b] = c ? atomicAdd(&cur[b], c) : 0;
    }
    for (int b = t; b < NB; b += 256) cnt[b] = 0;
    __syncthreads();

    // pass 2: stage into LDS in bucket-grouped order
    #pragma unroll
    for (int j = 0; j < 16; ++j) {
        int e = e0 + j * 256 + t;
        if (e < N_EDGES) {
            int dv = dst[e];
            int b = dv >> BSHIFT;
            int r = atomicAdd(&cnt[b], 1);
            int pos = bl[b] + r;
            stage[pos] = make_int2(((dv & (NPB - 1)) << 21) | (rel[e] << 16) | src[e],
                                   __float_as_int(norm[e]));
            bid[pos] = (unsigned short)b;
        }
    }
    __syncthreads();

    // pass 3: burst write to global reserved ranges (coalesced runs)
    const int total = bl[NB];
    for (int p = t; p < total; p += 256) {
        int b = bid[p];
        pay[gb[b] + (p - bl[b])] = stage[p];
    }
}

// One block per bucket: stage edges in LDS, counting-sort by 8-bit key
// (sub-bucket dl>>4, rel) with per-wave counters, write back IN PLACE,
// emit absolute run boundaries runs[b][0..256]. s = b*BCAP, e = cur[b].
__global__ __launch_bounds__(512) void k_sort(
        const int* __restrict__ cur, int2* __restrict__ pay,
        int* __restrict__ runs) {
    __shared__ int2 stage[SORT_CAP];   // 48 KB
    __shared__ int cnt[8][NKEY];       // 8 KB
    __shared__ int wb[8][NKEY];        // 8 KB
    __shared__ int kbase[NKEY];
    __shared__ int wsum[8];

    const int t = threadIdx.x;
    const int lane = t & 63;
    const int w = t >> 6;
    const int b = blockIdx.x;
    const int s = b * BCAP;
    const int e = cur[b];
    const int n = min(e - s, SORT_CAP);   // clamp: overflow degrades, never faults

    for (int j = t; j < 8 * NKEY; j += 512) ((int*)cnt)[j] = 0;
    __syncthreads();

    // stage + per-wave count
    for (int j = t; j < n; j += 512) {
        int2 p = pay[s + j];
        stage[j] = p;
        int key = (((p.x >> 25) & 7) << 5) | ((p.x >> 16) & 31);
        atomicAdd(&cnt[w][key], 1);
    }
    __syncthreads();

    // key totals + block-wide exclusive scan over 256 keys
    int tot = 0;
    if (t < NKEY) {
        #pragma unroll
        for (int ww = 0; ww < 8; ++ww) tot += cnt[ww][t];
    }
    int x = tot;
    #pragma unroll
    for (int d = 1; d < 64; d <<= 1) {
        int nn = __shfl_up(x, d, 64);
        if (lane >= d) x += nn;
    }
    if (lane == 63) wsum[w] = x;
    __syncthreads();
    if (t == 0) {
        int run = 0;
        #pragma unroll
        for (int i = 0; i < 8; ++i) { int tmp = wsum[i]; wsum[i] = run; run += tmp; }
    }
    __syncthreads();
    int excl = x - tot + wsum[w];
    if (t < NKEY) kbase[t] = excl;
    __syncthreads();

    // per-wave scatter bases + emit runs
    if (t < NKEY) {
        int run = kbase[t];
        #pragma unroll
        for (int ww = 0; ww < 8; ++ww) { wb[ww][t] = run; run += cnt[ww][t]; }
        runs[b * (NKEY + 1) + t] = s + kbase[t];
    }
    if (t == 0) runs[b * (NKEY + 1) + NKEY] = s + n;
    // barrier BEFORE re-zeroing cnt (v12 race lesson: wb reads all of cnt)
    __syncthreads();
    for (int j = t; j < 8 * NKEY; j += 512) ((int*)cnt)[j] = 0;
    __syncthreads();

    // rank & scatter back in place, key-sorted
    for (int j = t; j < n; j += 512) {
        int2 p = stage[j];
        int key = (((p.x >> 25) & 7) << 5) | ((p.x >> 16) & 31);
        int pos = wb[w][key] + atomicAdd(&cnt[w][key], 1);
        pay[s + pos] = p;
    }
}

// Fused per-bucket GEMM with chained-MFMA dst-scatter, lockstep-rel Wfrag
// staging, and a 2-deep software pipeline over (run,tile) items:
//   item i computing | item i+1 hrow gathers in flight | item i+2 pay in flight
// Loads cross the per-rel barrier legally (only wbuf ds_reads are ordered).
// 512 thr / 8 waves; wave sb owns sub-bucket sb, accumulates all 32 rels.
__global__ __launch_bounds__(512) void k_fuse(
        const unsigned short* __restrict__ hbf, const __bf16* __restrict__ Wfrag,
        const int* __restrict__ runs, const int2* __restrict__ pay,
        float* __restrict__ out) {
    __shared__ int runsL[NKEY + 1];
    __shared__ __align__(16) unsigned short wbuf[2][4096];   // 16 KB

    const int t = threadIdx.x;
    const int lane = t & 63;
    const int w = t >> 6;        // sub-bucket 0..7
    const int m = lane & 15;
    const int q = lane >> 4;
    const int b = blockIdx.x;

    for (int j = t; j < NKEY + 1; j += 512) runsL[j] = runs[b * (NKEY + 1) + j];
    ((bf16x8*)wbuf[0])[t] = ((const bf16x8*)Wfrag)[t];
    __syncthreads();

    const f32x4 vzero = {0.f, 0.f, 0.f, 0.f};
    f32x4 acc2[4];
    #pragma unroll
    for (int ot = 0; ot < 4; ++ot) acc2[ot] = vzero;

    const int kb = w * 32;

    // ---- pipeline state ----
    int pr = 0, ptl = 0, prs = 0, pre_ = 0;
    while (pr < N_REL) { prs = runsL[kb + pr]; pre_ = runsL[kb + pr + 1]; if (pre_ > prs) break; ++pr; }

    int cr = N_REL, cmask = 0;       // current item (compute-ready)
    int2 p_cur; bf16x8 a0c, a1c;
    int nrel = N_REL, nmask = 0;     // next item (payload in flight)
    int2 p_nxt;

    if (pr < N_REL) {
        int ei = prs + ptl * 16 + m;
        p_cur = pay[min(ei, pre_ - 1)];
        cmask = (ei < pre_);
        cr = pr;
        ++ptl;
        if (prs + ptl * 16 >= pre_) {
            ++pr; ptl = 0;
            while (pr < N_REL) { prs = runsL[kb + pr]; pre_ = runsL[kb + pr + 1]; if (pre_ > prs) break; ++pr; }
        }
        const unsigned short* hrow = hbf + ((size_t)(p_cur.x & 0xFFFF) << 6);
        a0c = *(const bf16x8*)(hrow + q * 8);
        a1c = *(const bf16x8*)(hrow + 32 + q * 8);
        if (pr < N_REL) {
            int ei2 = prs + ptl * 16 + m;
            p_nxt = pay[min(ei2, pre_ - 1)];
            nmask = (ei2 < pre_);
            nrel = pr;
            ++ptl;
            if (prs + ptl * 16 >= pre_) {
                ++pr; ptl = 0;
                while (pr < N_REL) { prs = runsL[kb + pr]; pre_ = runsL[kb + pr + 1]; if (pre_ > prs) break; ++pr; }
            }
        }
    }

    for (int r = 0; r < N_REL; ++r) {
        bf16x8 stg;
        if (r + 1 < N_REL) stg = ((const bf16x8*)Wfrag)[(r + 1) * 512 + t];

        if (cr == r) {
            const unsigned short* wbp = wbuf[r & 1];
            bf16x8 wf[2][4];
            #pragma unroll
            for (int kt = 0; kt < 2; ++kt)
                #pragma unroll
                for (int ot = 0; ot < 4; ++ot)
                    wf[kt][ot] = *(const bf16x8*)(wbp + ((kt * 4 + ot) * 64 + lane) * 8);

            while (cr == r) {
                int2 p_b = p_nxt;
                int brel = nrel, bmask = nmask;
                bf16x8 a0n, a1n;
                if (brel < N_REL) {
                    const unsigned short* hrn = hbf + ((size_t)(p_b.x & 0xFFFF) << 6);
                    a0n = *(const bf16x8*)(hrn + q * 8);
                    a1n = *(const bf16x8*)(hrn + 32 + q * 8);
                }
                if (pr < N_REL) {
                    int ei2 = prs + ptl * 16 + m;
                    p_nxt = pay[min(ei2, pre_ - 1)];
                    nmask = (ei2 < pre_);
                    nrel = pr;
                    ++ptl;
                    if (prs + ptl * 16 >= pre_) {
                        ++pr; ptl = 0;
                        while (pr < N_REL) { prs = runsL[kb + pr]; pre_ = runsL[kb + pr + 1]; if (pre_ > prs) break; ++pr; }
                    }
                } else {
                    nrel = N_REL;
                }

                float nvf = cmask ? __int_as_float(p_cur.y) : 0.f;
                int meta = (((p_cur.x >> 21) & 15) << 16) | f16_bits((_Float16)nvf);

                f32x4 c1[4];
                #pragma unroll
                for (int ot = 0; ot < 4; ++ot) {
                    c1[ot] = __builtin_amdgcn_mfma_f32_16x16x32_bf16(a0c, wf[0][ot], vzero, 0, 0, 0);
                    c1[ot] = __builtin_amdgcn_mfma_f32_16x16x32_bf16(a1c, wf[1][ot], c1[ot], 0, 0, 0);
                }

                f16x4 a2;
                #pragma unroll
                for (int j = 0; j < 4; ++j) {
                    int sm = __shfl(meta, q * 4 + j, 64);
                    _Float16 nv = bits_f16((unsigned short)(sm & 0xFFFF));
                    a2[j] = ((sm >> 16) == m) ? nv : (_Float16)0.f;
                }

                #pragma unroll
                for (int ot = 0; ot < 4; ++ot) {
                    f16x4 b2;
                    b2[0] = (_Float16)c1[ot][0];
                    b2[1] = (_Float16)c1[ot][1];
                    b2[2] = (_Float16)c1[ot][2];
                    b2[3] = (_Float16)c1[ot][3];
                    acc2[ot] = __builtin_amdgcn_mfma_f32_16x16x16f16(a2, b2, acc2[ot], 0, 0, 0);
                }

                p_cur = p_b; cmask = bmask; cr = brel;
                a0c = a0n; a1c = a1n;
            }
        }

        if (r + 1 < N_REL) ((bf16x8*)wbuf[(r + 1) & 1])[t] = stg;
        __syncthreads();
    }

    // epilogue: lane(m,q) holds acc2[ot][reg] = out[sb*16 + q*4+reg][ot*16+m]
    const int node_base = b * NPB + w * 16;
    #pragma unroll
    for (int reg = 0; reg < 4; ++reg) {
        int node = node_base + q * 4 + reg;
        if (node < N_NODES) {
            float* orow = out + (size_t)node * D + m;
            #pragma unroll
            for (int ot = 0; ot < 4; ++ot)
                orow[ot * 16] = acc2[ot][reg];
        }
    }
}

extern "C" void kernel_launch(void* const* d_in, const int* in_sizes, int n_in,
                              void* d_out, int out_size, void* d_ws, size_t ws_size,
                              hipStream_t stream) {
    const float* h    = (const float*)d_in[0];
    const float* W    = (const float*)d_in[1];
    const int*   src  = (const int*)d_in[2];
    const int*   dst  = (const int*)d_in[3];
    const int*   rel  = (const int*)d_in[4];
    const float* norm = (const float*)d_in[5];
    float* out = (float*)d_out;

    char* ws = (char*)d_ws;
    int*    cur   = (int*)(ws + 0x2000);
    int*    runs  = (int*)(ws + 0x3000);
    int2*   pay   = (int2*)(ws + 0x100000);
    __bf16* Wfrag = (__bf16*)(ws + 0x1400000);
    __bf16* hbf   = (__bf16*)(ws + 0x1480000);

    k_init<<<INIT_BLOCKS, 512, 0, stream>>>(h, hbf, W, Wfrag, cur);
    k_scatter2<<<SC_BLOCKS, 256, 0, stream>>>(src, dst, rel, norm, cur, pay);
    k_sort<<<NB, 512, 0, stream>>>(cur, pay, runs);
    k_fuse<<<NB, 512, 0, stream>>>((const unsigned short*)hbf, Wfrag, runs, pay, out);
}